// Round 1
// baseline (358.404 us; speedup 1.0000x reference)
//
#include <hip/hip_runtime.h>
#include <hip/hip_bf16.h>

// Problem: B=2, S=2048, D=1024, H=16, DH=64.  out = MHA(q,k,v) @ wo.T
// All f32 inputs; we cast to bf16 and use 16x16x32 bf16 MFMA with f32 accum.

typedef __bf16 bf16x8 __attribute__((ext_vector_type(8)));
typedef float f32x4 __attribute__((ext_vector_type(4)));

#define AS1 __attribute__((address_space(1)))
#define AS3 __attribute__((address_space(3)))

__device__ __forceinline__ void load_lds16(const void* g, void* l) {
    __builtin_amdgcn_global_load_lds((const AS1 void*)g, (AS3 void*)l, 16, 0, 0);
}

__device__ __forceinline__ void stc(float* p, float v) { *p = v; }
__device__ __forceinline__ void stc(__hip_bfloat16* p, float v) { *p = __float2bfloat16(v); }

// ---------------- f32 -> bf16 cast (vectorized) ----------------
__global__ __launch_bounds__(256) void cast_bf16(const float* __restrict__ s,
                                                 __hip_bfloat16* __restrict__ d, int n4) {
    int i = blockIdx.x * 256 + threadIdx.x;
    if (i >= n4) return;
    float4 v = reinterpret_cast<const float4*>(s)[i];
    union { __hip_bfloat16 h[4]; short4 s4; } u;
    u.h[0] = __float2bfloat16(v.x);
    u.h[1] = __float2bfloat16(v.y);
    u.h[2] = __float2bfloat16(v.z);
    u.h[3] = __float2bfloat16(v.w);
    reinterpret_cast<short4*>(d)[i] = u.s4;
}

// ---------------- GEMM: C[M,N] = alpha * A[M,K] @ W[N,K]^T ----------------
// M=4096, N=1024, K=1024 for every projection in this problem.
// m97 structure: 128x128 tile, BK=32, 4 waves each owning a 64x64 quadrant,
// global_load_lds width=16 staging, 16 MFMA + 8 ds_read_b128 per K-step.
template <typename OutT>
__global__ __launch_bounds__(256) void gemm_bt(const __hip_bfloat16* __restrict__ Ab,
                                               const __hip_bfloat16* __restrict__ Wb,
                                               OutT* __restrict__ Cb, float alpha_z0) {
    constexpr int Mn = 4096, Nn = 1024, Kn = 1024, BM = 128, BN = 128, BK = 32;
    const int z = blockIdx.z;
    const float alpha = (z == 0) ? alpha_z0 : 1.0f;
    const __hip_bfloat16* A = Ab + (size_t)z * Mn * Kn;
    const __hip_bfloat16* W = Wb + (size_t)z * Nn * Kn;
    OutT* C = Cb + (size_t)z * Mn * Nn;

    __shared__ __hip_bfloat16 sA[BM * BK];  // 8 KB, linear for global_load_lds
    __shared__ __hip_bfloat16 sB[BN * BK];  // 8 KB

    const int t = threadIdx.x, w = t >> 6, l = t & 63;
    const int lr = l & 15, lk = (l >> 4) * 8;
    const int mbase = blockIdx.y * BM, nbase = blockIdx.x * BN;
    const int wr = (w >> 1) * 64, wc = (w & 1) * 64;

    f32x4 acc[4][4] = {};

    for (int k0 = 0; k0 < Kn; k0 += BK) {
#pragma unroll
        for (int i = 0; i < 2; i++) {
            const int c = i * 256 + t;  // 16B chunk index; row=c>>2, colchunk=c&3
            load_lds16(&A[(size_t)(mbase + (c >> 2)) * Kn + k0 + (c & 3) * 8],
                       &sA[(i * 256 + w * 64) * 8]);
            load_lds16(&W[(size_t)(nbase + (c >> 2)) * Kn + k0 + (c & 3) * 8],
                       &sB[(i * 256 + w * 64) * 8]);
        }
        __syncthreads();
        bf16x8 af[4], bfr[4];
#pragma unroll
        for (int m = 0; m < 4; m++) af[m] = *(const bf16x8*)&sA[(wr + m * 16 + lr) * BK + lk];
#pragma unroll
        for (int n = 0; n < 4; n++) bfr[n] = *(const bf16x8*)&sB[(wc + n * 16 + lr) * BK + lk];
#pragma unroll
        for (int m = 0; m < 4; m++)
#pragma unroll
            for (int n = 0; n < 4; n++)
                acc[m][n] = __builtin_amdgcn_mfma_f32_16x16x32_bf16(af[m], bfr[n], acc[m][n], 0, 0, 0);
        __syncthreads();
    }

    // C/D layout: col = lane&15, row = (lane>>4)*4 + reg
    const int row0 = mbase + wr + (l >> 4) * 4;
    const int col0 = nbase + wc + lr;
#pragma unroll
    for (int m = 0; m < 4; m++)
#pragma unroll
        for (int n = 0; n < 4; n++)
#pragma unroll
            for (int r = 0; r < 4; r++)
                stc(&C[(size_t)(row0 + m * 16 + r) * Nn + col0 + n * 16], acc[m][n][r] * alpha);
}

// ---------------- causal flash attention ----------------
// Q,K,V: bf16 [B,S,H,DH] (row stride D=1024). Scores scale already folded into Q.
// Block = 4 waves; wave w owns 16 q-rows; Q-tile = 64 rows; KV tiles of 64.
__global__ __launch_bounds__(256) void attn_causal(const __hip_bfloat16* __restrict__ Q,
                                                   const __hip_bfloat16* __restrict__ K,
                                                   const __hip_bfloat16* __restrict__ V,
                                                   __hip_bfloat16* __restrict__ X) {
    constexpr int S = 2048, D = 1024, DH = 64;
    const int qt = blockIdx.x;          // 0..31 (q-tile of 64 rows)
    const int bh = blockIdx.y;          // 0..31
    const int b = bh >> 4, h = bh & 15;

    __shared__ __hip_bfloat16 Ks[64][72];       // K tile row-major [kv][dh], padded
    __shared__ __hip_bfloat16 Vt[64][72];       // V tile transposed [dh][kv], padded
    __shared__ __hip_bfloat16 Pl[4][16][72];    // per-wave P tile [qrow][kv], padded

    const int t = threadIdx.x, w = t >> 6, l = t & 63;
    const int lr = l & 15, lk = (l >> 4) * 8;

    const __hip_bfloat16* Qb = Q + ((size_t)b * S) * D + (size_t)h * DH;
    const __hip_bfloat16* Kb = K + ((size_t)b * S) * D + (size_t)h * DH;
    const __hip_bfloat16* Vb = V + ((size_t)b * S) * D + (size_t)h * DH;

    const int qrow = qt * 64 + w * 16;  // this wave's first q row

    // preload Q fragments (A-operand: row = lane&15, k = (lane>>4)*8 + j)
    bf16x8 qf[2];
#pragma unroll
    for (int kk = 0; kk < 2; kk++)
        qf[kk] = *(const bf16x8*)&Qb[(size_t)(qrow + lr) * D + kk * 32 + lk];

    f32x4 xacc[4] = {};
    float mrow[4], lrow[4];
#pragma unroll
    for (int r = 0; r < 4; r++) { mrow[r] = -1e30f; lrow[r] = 0.f; }

    for (int kt = 0; kt <= qt; ++kt) {
        // ---- stage K (row-major) and V (transposed) ----
        const __hip_bfloat16* Kg = Kb + (size_t)(kt * 64) * D;
        const __hip_bfloat16* Vg = Vb + (size_t)(kt * 64) * D;
#pragma unroll
        for (int i = 0; i < 2; i++) {
            const int c = i * 256 + t;        // 512 chunks of 8 elems = 64x64
            const int rr = c >> 3, c8 = c & 7;
            uint4 kv4 = *(const uint4*)&Kg[(size_t)rr * D + c8 * 8];
            *(uint4*)&Ks[rr][c8 * 8] = kv4;
            union { uint4 u; __hip_bfloat16 hh[8]; } vu;
            vu.u = *(const uint4*)&Vg[(size_t)rr * D + c8 * 8];
#pragma unroll
            for (int j = 0; j < 8; j++) Vt[c8 * 8 + j][rr] = vu.hh[j];
        }
        __syncthreads();

        // ---- scores: S[16 q][64 kv] via 8 MFMAs ----
        f32x4 sacc[4] = {};
#pragma unroll
        for (int kk = 0; kk < 2; kk++)
#pragma unroll
            for (int n = 0; n < 4; n++) {
                bf16x8 bfr = *(const bf16x8*)&Ks[n * 16 + lr][kk * 32 + lk];
                sacc[n] = __builtin_amdgcn_mfma_f32_16x16x32_bf16(qf[kk], bfr, sacc[n], 0, 0, 0);
            }

        // ---- causal mask on diagonal tile ----
        if (kt == qt) {
#pragma unroll
            for (int n = 0; n < 4; n++)
#pragma unroll
                for (int r = 0; r < 4; r++) {
                    int qg = qrow + (l >> 4) * 4 + r;
                    int kv = kt * 64 + n * 16 + lr;
                    if (kv > qg) sacc[n][r] = -1e30f;
                }
        }

        // ---- online softmax update (rows live on 16-lane groups) ----
        float pr[4][4], scale[4];
#pragma unroll
        for (int r = 0; r < 4; r++) {
            float tm = fmaxf(fmaxf(sacc[0][r], sacc[1][r]), fmaxf(sacc[2][r], sacc[3][r]));
#pragma unroll
            for (int mm = 8; mm >= 1; mm >>= 1) tm = fmaxf(tm, __shfl_xor(tm, mm, 64));
            float mn = fmaxf(mrow[r], tm);
            scale[r] = __expf(mrow[r] - mn);
            mrow[r] = mn;
            float ps = 0.f;
#pragma unroll
            for (int n = 0; n < 4; n++) {
                float p = __expf(sacc[n][r] - mn);
                pr[n][r] = p;
                ps += p;
            }
#pragma unroll
            for (int mm = 8; mm >= 1; mm >>= 1) ps += __shfl_xor(ps, mm, 64);
            lrow[r] = lrow[r] * scale[r] + ps;
#pragma unroll
            for (int d = 0; d < 4; d++) xacc[d][r] *= scale[r];
        }

        // ---- P -> LDS (C-layout scatter), re-fragment as A-operand ----
#pragma unroll
        for (int n = 0; n < 4; n++)
#pragma unroll
            for (int r = 0; r < 4; r++)
                Pl[w][(l >> 4) * 4 + r][n * 16 + lr] = __float2bfloat16(pr[n][r]);
        __syncthreads();  // orders intra-wave LDS write->read (compiler-safe)

        // ---- PV: x[16 q][64 dh] += P[16 q][64 kv] @ V[64 kv][64 dh] ----
#pragma unroll
        for (int d = 0; d < 4; d++)
#pragma unroll
            for (int kk = 0; kk < 2; kk++) {
                bf16x8 pa = *(const bf16x8*)&Pl[w][lr][kk * 32 + lk];
                bf16x8 vb = *(const bf16x8*)&Vt[d * 16 + lr][kk * 32 + lk];
                xacc[d] = __builtin_amdgcn_mfma_f32_16x16x32_bf16(pa, vb, xacc[d], 0, 0, 0);
            }
        __syncthreads();  // protect Ks/Vt before next tile's staging
    }

    // ---- epilogue: divide by l, store bf16 [B,S,H,DH] ----
    __hip_bfloat16* Xg = X + ((size_t)b * S) * D + (size_t)h * DH;
#pragma unroll
    for (int r = 0; r < 4; r++) {
        float inv = 1.0f / lrow[r];
        int qg = qrow + (l >> 4) * 4 + r;
#pragma unroll
        for (int d = 0; d < 4; d++)
            Xg[(size_t)qg * D + d * 16 + lr] = __float2bfloat16(xacc[d][r] * inv);
    }
}

// ---------------- launch ----------------
extern "C" void kernel_launch(void* const* d_in, const int* in_sizes, int n_in,
                              void* d_out, int out_size, void* d_ws, size_t ws_size,
                              hipStream_t stream) {
    const float* q_in = (const float*)d_in[0];
    const float* k_in = (const float*)d_in[1];
    const float* v_in = (const float*)d_in[2];
    // d_in[3] = causal mask — always tril, exploited structurally, never read
    const float* wq = (const float*)d_in[4];
    const float* wk = (const float*)d_in[5];
    const float* wv = (const float*)d_in[6];
    const float* wo = (const float*)d_in[7];

    const size_t MD = (size_t)4096 * 1024;  // 4,194,304 elems per [B,S,D] tensor
    const size_t WD = (size_t)1024 * 1024;  // 1,048,576 elems per weight

    __hip_bfloat16* ws = (__hip_bfloat16*)d_ws;
    __hip_bfloat16* inb = ws;                     // q,k,v inputs bf16   (3*MD)
    __hip_bfloat16* wb = ws + 3 * MD;             // wq,wk,wv,wo bf16    (4*WD)
    __hip_bfloat16* qkv = wb + 4 * WD;            // Q,K,V               (3*MD)
    __hip_bfloat16* xb = qkv + 3 * MD;            // attention output    (MD)

    // casts
    cast_bf16<<<4096, 256, 0, stream>>>(q_in, inb, (int)(MD / 4));
    cast_bf16<<<4096, 256, 0, stream>>>(k_in, inb + MD, (int)(MD / 4));
    cast_bf16<<<4096, 256, 0, stream>>>(v_in, inb + 2 * MD, (int)(MD / 4));
    cast_bf16<<<1024, 256, 0, stream>>>(wq, wb, (int)(WD / 4));
    cast_bf16<<<1024, 256, 0, stream>>>(wk, wb + WD, (int)(WD / 4));
    cast_bf16<<<1024, 256, 0, stream>>>(wv, wb + 2 * WD, (int)(WD / 4));
    cast_bf16<<<1024, 256, 0, stream>>>(wo, wb + 3 * WD, (int)(WD / 4));

    // fused QKV projections (z: 0=Q with 1/8 score scale folded in, 1=K, 2=V)
    gemm_bt<__hip_bfloat16><<<dim3(8, 32, 3), 256, 0, stream>>>(inb, wb, qkv, 0.125f);

    // causal attention
    attn_causal<<<dim3(32, 32), 256, 0, stream>>>(qkv, qkv + MD, qkv + 2 * MD, xb);

    // output projection -> f32 d_out
    gemm_bt<float><<<dim3(8, 32, 1), 256, 0, stream>>>(xb, wb + 3 * WD, (float*)d_out, 1.0f);
}

// Round 3
// 251.480 us; speedup vs baseline: 1.4252x; 1.4252x over previous
//
#include <hip/hip_runtime.h>
#include <hip/hip_bf16.h>

// B=2, S=2048, D=1024, H=16, DH=64.  out = causal-MHA(q,k,v) @ wo.T
// bf16 MFMA path, f32 accumulation everywhere.

typedef __bf16 bf16x8 __attribute__((ext_vector_type(8)));
typedef float f32x4 __attribute__((ext_vector_type(4)));

#define AS1 __attribute__((address_space(1)))
#define AS3 __attribute__((address_space(3)))

__device__ __forceinline__ void load_lds16(const void* g, void* l) {
    __builtin_amdgcn_global_load_lds((const AS1 void*)g, (AS3 void*)l, 16, 0, 0);
}

// ---------------- f32 -> bf16 casts, up to 4 tensors per launch ----------------
__global__ __launch_bounds__(256) void cast_many(const float* __restrict__ a0,
                                                 const float* __restrict__ a1,
                                                 const float* __restrict__ a2,
                                                 const float* __restrict__ a3,
                                                 __hip_bfloat16* __restrict__ d,
                                                 size_t per, int n4) {
    const float* s = (blockIdx.y == 0) ? a0 : (blockIdx.y == 1) ? a1 : (blockIdx.y == 2) ? a2 : a3;
    d += (size_t)blockIdx.y * per;
    int i = blockIdx.x * 256 + threadIdx.x;
    if (i >= n4) return;
    float4 v = reinterpret_cast<const float4*>(s)[i];
    union { __hip_bfloat16 h[4]; short4 s4; } u;
    u.h[0] = __float2bfloat16(v.x);
    u.h[1] = __float2bfloat16(v.y);
    u.h[2] = __float2bfloat16(v.z);
    u.h[3] = __float2bfloat16(v.w);
    reinterpret_cast<short4*>(d)[i] = u.s4;
}

// ---------------- GEMM: C[M,N] = A[M,K] @ W[N,K]^T ----------------
// MODE 0: plain f32 output [4096][1024] (out projection), A = Ab.
// MODE 1: fused QKV (N=3072). A selected per n-region (query/key/value inputs).
//   region 0 -> Qb bf16 [4096][1024], scaled by 0.125 (1/sqrt(DH))
//   region 1 -> Kb bf16 [4096][1024]
//   region 2 -> Vtb bf16 [32 bh][64 dh][2048 s]  (transposed in epilogue)
template <int BM, int MODE>
__global__ __launch_bounds__(256) void gemm_bt(const __hip_bfloat16* __restrict__ Ab,
                                               const __hip_bfloat16* __restrict__ Wb,
                                               float* __restrict__ Cf,
                                               __hip_bfloat16* __restrict__ Qb,
                                               __hip_bfloat16* __restrict__ Kb,
                                               __hip_bfloat16* __restrict__ Vtb) {
    constexpr int Kn = 1024, BK = 32, MW = BM / 32;
    constexpr size_t MD = (size_t)4096 * 1024;

    __shared__ __hip_bfloat16 sA[BM * BK];
    __shared__ __hip_bfloat16 sB[128 * BK];

    const int t = threadIdx.x, w = t >> 6, l = t & 63;
    const int lr = l & 15, lk = (l >> 4) * 8;
    const int mbase = blockIdx.y * BM, nbase = blockIdx.x * 128;
    const int wr = (w >> 1) * (BM / 2), wc = (w & 1) * 64;

    const __hip_bfloat16* A = Ab;
    if constexpr (MODE == 1) A = Ab + (size_t)(nbase >> 10) * MD;

    f32x4 acc[MW][4] = {};

    for (int k0 = 0; k0 < Kn; k0 += BK) {
#pragma unroll
        for (int i = 0; i < BM / 64; i++) {
            const int c = i * 256 + t;
            load_lds16(&A[(size_t)(mbase + (c >> 2)) * Kn + k0 + (c & 3) * 8],
                       &sA[(i * 256 + w * 64) * 8]);
        }
#pragma unroll
        for (int i = 0; i < 2; i++) {
            const int c = i * 256 + t;
            load_lds16(&Wb[(size_t)(nbase + (c >> 2)) * Kn + k0 + (c & 3) * 8],
                       &sB[(i * 256 + w * 64) * 8]);
        }
        __syncthreads();
        bf16x8 af[MW], bfr[4];
#pragma unroll
        for (int m = 0; m < MW; m++) af[m] = *(const bf16x8*)&sA[(wr + m * 16 + lr) * BK + lk];
#pragma unroll
        for (int n = 0; n < 4; n++) bfr[n] = *(const bf16x8*)&sB[(wc + n * 16 + lr) * BK + lk];
#pragma unroll
        for (int m = 0; m < MW; m++)
#pragma unroll
            for (int n = 0; n < 4; n++)
                acc[m][n] = __builtin_amdgcn_mfma_f32_16x16x32_bf16(af[m], bfr[n], acc[m][n], 0, 0, 0);
        __syncthreads();
    }

    // C/D layout: col = lane&15, row = (lane>>4)*4 + reg
    const int row0 = mbase + wr + (l >> 4) * 4;
    if constexpr (MODE == 0) {
#pragma unroll
        for (int m = 0; m < MW; m++)
#pragma unroll
            for (int n = 0; n < 4; n++)
#pragma unroll
                for (int r = 0; r < 4; r++)
                    Cf[(size_t)(row0 + m * 16 + r) * 1024 + nbase + wc + n * 16 + lr] = acc[m][n][r];
    } else {
        const int region = nbase >> 10;
        const int colL = (nbase & 1023) + wc + lr;  // + n*16
        if (region < 2) {
            __hip_bfloat16* Ob = (region == 0) ? Qb : Kb;
            const float alpha = (region == 0) ? 0.125f : 1.0f;
#pragma unroll
            for (int m = 0; m < MW; m++)
#pragma unroll
                for (int n = 0; n < 4; n++)
#pragma unroll
                    for (int r = 0; r < 4; r++)
                        Ob[(size_t)(row0 + m * 16 + r) * 1024 + colL + n * 16] =
                            __float2bfloat16(acc[m][n][r] * alpha);
        } else {
            // V^T: Vtb[(b*16+h)*64 + dh][s], 4 consecutive tokens pack into 8B
#pragma unroll
            for (int m = 0; m < MW; m++) {
                const int s0 = row0 + m * 16;          // token (mult of 4)
                const int b = s0 >> 11, s = s0 & 2047;
#pragma unroll
                for (int n = 0; n < 4; n++) {
                    const int dhg = colL + n * 16;      // 0..1023
                    const size_t idx = ((size_t)((b * 16 + (dhg >> 6)) * 64 + (dhg & 63))) * 2048 + s;
                    union { __hip_bfloat16 h[4]; short4 s4; } u;
#pragma unroll
                    for (int r = 0; r < 4; r++) u.h[r] = __float2bfloat16(acc[m][n][r]);
                    *(short4*)&Vtb[idx] = u.s4;
                }
            }
        }
    }
}

// ---------------- causal flash attention ----------------
// Q,K dense bf16 [4096][1024] (token-major, head at col h*64); V^T [bh][64][2048].
// Block = 4 waves, 64 q-rows; processes q-tile pair (p, 31-p) -> uniform 33 KV steps.
// K/V tiles [64][64] double-buffered in LDS, XOR-swizzled (T2), staged via
// global_load_lds with pre-swizzled source; counted vmcnt pipeline (T3/T4).
__device__ __forceinline__ bf16x8 rd8(const __hip_bfloat16* tile, int row, int colb) {
    return *(const bf16x8*)((const char*)tile + row * 128 + (colb ^ ((row & 7) << 4)));
}

__device__ __forceinline__ void stage_kv(const char* Kg, const char* Vg, void* ksb, void* vsb, int t) {
#pragma unroll
    for (int i = 0; i < 2; i++) {
        const int c = i * 256 + t, row = c >> 3;
        const int colb = ((c & 7) * 16) ^ ((row & 7) << 4);
        load_lds16(Kg + (size_t)row * 2048 + colb, (char*)ksb + (i * 256 + (t & 192)) * 16);
    }
#pragma unroll
    for (int i = 0; i < 2; i++) {
        const int c = i * 256 + t, row = c >> 3;
        const int colb = ((c & 7) * 16) ^ ((row & 7) << 4);
        load_lds16(Vg + (size_t)row * 4096 + colb, (char*)vsb + (i * 256 + (t & 192)) * 16);
    }
}

__global__ __launch_bounds__(256) void attn_causal(const __hip_bfloat16* __restrict__ Qb,
                                                   const __hip_bfloat16* __restrict__ Kb,
                                                   const __hip_bfloat16* __restrict__ Vtb,
                                                   __hip_bfloat16* __restrict__ X) {
    constexpr int S = 2048;
    // bijective XCD swizzle: same bh contiguous within an XCD chunk
    const int d0 = blockIdx.x;
    const int within = d0 >> 3;
    const int bh = (d0 & 7) * 4 + (within >> 4);
    const int p = within & 15;
    const int b = bh >> 4, h = bh & 15;
    const int qtA = p, qtB = 31 - p;

    __shared__ __hip_bfloat16 Ks[2][4096];  // [64 kv][64 dh] swizzled
    __shared__ __hip_bfloat16 Vs[2][4096];  // [64 dh][64 kv] swizzled
    __shared__ __hip_bfloat16 Pl[4 * 1024]; // per-wave [16 q][64 kv] swizzled

    const int t = threadIdx.x, w = t >> 6, l = t & 63;
    const int lr = l & 15, lg = l >> 4, lk = lg * 8;

    const __hip_bfloat16* Qbh = Qb + (size_t)b * S * 1024 + h * 64;
    const char* Kbh = (const char*)(Kb + (size_t)b * S * 1024 + h * 64);
    const char* Vbh = (const char*)(Vtb + (size_t)bh * 64 * 2048);
    __hip_bfloat16* Xbh = X + (size_t)b * S * 1024 + h * 64;

    int qt = qtA;
    int qrow = qt * 64 + w * 16;
    bf16x8 qf[2];
#pragma unroll
    for (int kk = 0; kk < 2; kk++)
        qf[kk] = *(const bf16x8*)&Qbh[(size_t)(qrow + lr) * 1024 + kk * 32 + lk];

    f32x4 xacc[4] = {};
    float mrow[4], lrow[4];
#pragma unroll
    for (int r = 0; r < 4; r++) { mrow[r] = -1e30f; lrow[r] = 0.f; }

    // prologue: stage tile 0 into buf 0
    stage_kv(Kbh, Vbh, &Ks[0][0], &Vs[0][0], t);

    const int total = 33;  // (qtA+1) + (qtB+1)
    int kt = 0;
    for (int i = 0; i < total; ++i) {
        if (i + 1 < total) {
            const int ktn = (i + 1 <= qtA) ? i + 1 : i - qtA;
            stage_kv(Kbh + (size_t)(ktn * 64) * 2048, Vbh + (size_t)ktn * 128,
                     &Ks[(i + 1) & 1][0], &Vs[(i + 1) & 1][0], t);
            asm volatile("s_waitcnt vmcnt(4)" ::: "memory");
        } else {
            asm volatile("s_waitcnt vmcnt(0)" ::: "memory");
        }
        __builtin_amdgcn_s_barrier();

        const __hip_bfloat16* Kt = &Ks[i & 1][0];
        const __hip_bfloat16* Vt = &Vs[i & 1][0];

        // ---- QK^T: S[16 q][64 kv] ----
        f32x4 sacc[4] = {};
#pragma unroll
        for (int kk = 0; kk < 2; kk++)
#pragma unroll
            for (int n = 0; n < 4; n++)
                sacc[n] = __builtin_amdgcn_mfma_f32_16x16x32_bf16(
                    qf[kk], rd8(Kt, n * 16 + lr, kk * 64 + lg * 16), sacc[n], 0, 0, 0);

        // ---- causal mask on diagonal tile ----
        if (kt == qt) {
#pragma unroll
            for (int n = 0; n < 4; n++)
#pragma unroll
                for (int r = 0; r < 4; r++) {
                    const int qg = qrow + lg * 4 + r;
                    const int kv = kt * 64 + n * 16 + lr;
                    if (kv > qg) sacc[n][r] = -1e30f;
                }
        }

        // ---- online softmax (rows on 16-lane groups) ----
        float pr[4][4];
#pragma unroll
        for (int r = 0; r < 4; r++) {
            float tm = fmaxf(fmaxf(sacc[0][r], sacc[1][r]), fmaxf(sacc[2][r], sacc[3][r]));
#pragma unroll
            for (int mm = 8; mm >= 1; mm >>= 1) tm = fmaxf(tm, __shfl_xor(tm, mm, 64));
            const float mn = fmaxf(mrow[r], tm);
            const float sc = __expf(mrow[r] - mn);
            mrow[r] = mn;
            float ps = 0.f;
#pragma unroll
            for (int n = 0; n < 4; n++) {
                const float pv = __expf(sacc[n][r] - mn);
                pr[n][r] = pv;
                ps += pv;
            }
#pragma unroll
            for (int mm = 8; mm >= 1; mm >>= 1) ps += __shfl_xor(ps, mm, 64);
            lrow[r] = lrow[r] * sc + ps;
#pragma unroll
            for (int dd = 0; dd < 4; dd++) xacc[dd][r] *= sc;
        }

        // ---- P -> swizzled per-wave LDS tile ----
#pragma unroll
        for (int n = 0; n < 4; n++)
#pragma unroll
            for (int r = 0; r < 4; r++) {
                const int row = lg * 4 + r;
                *(__hip_bfloat16*)((char*)Pl + w * 2048 + row * 128 +
                                   ((n * 32 + lr * 2) ^ ((row & 7) << 4))) =
                    __float2bfloat16(pr[n][r]);
            }

        // ---- PV: x[16 q][64 dh] += P @ V ----
#pragma unroll
        for (int kk = 0; kk < 2; kk++) {
            const bf16x8 pa = *(const bf16x8*)((const char*)Pl + w * 2048 + lr * 128 +
                                               ((kk * 64 + lg * 16) ^ ((lr & 7) << 4)));
#pragma unroll
            for (int dd = 0; dd < 4; dd++)
                xacc[dd] = __builtin_amdgcn_mfma_f32_16x16x32_bf16(
                    pa, rd8(Vt, dd * 16 + lr, kk * 64 + lg * 16), xacc[dd], 0, 0, 0);
        }

        // ---- phase bookkeeping / epilogue of phase A ----
        if (i == qtA) {
#pragma unroll
            for (int r = 0; r < 4; r++) {
                const float inv = 1.0f / lrow[r];
#pragma unroll
                for (int dd = 0; dd < 4; dd++)
                    Xbh[(size_t)(qrow + lg * 4 + r) * 1024 + dd * 16 + lr] =
                        __float2bfloat16(xacc[dd][r] * inv);
            }
#pragma unroll
            for (int r = 0; r < 4; r++) { mrow[r] = -1e30f; lrow[r] = 0.f; }
#pragma unroll
            for (int dd = 0; dd < 4; dd++) xacc[dd] = f32x4{0.f, 0.f, 0.f, 0.f};
            qt = qtB;
            qrow = qt * 64 + w * 16;
#pragma unroll
            for (int kk = 0; kk < 2; kk++)
                qf[kk] = *(const bf16x8*)&Qbh[(size_t)(qrow + lr) * 1024 + kk * 32 + lk];
            kt = 0;
        } else {
            kt++;
        }
        __builtin_amdgcn_s_barrier();
    }

    // epilogue phase B
#pragma unroll
    for (int r = 0; r < 4; r++) {
        const float inv = 1.0f / lrow[r];
#pragma unroll
        for (int dd = 0; dd < 4; dd++)
            Xbh[(size_t)(qrow + lg * 4 + r) * 1024 + dd * 16 + lr] =
                __float2bfloat16(xacc[dd][r] * inv);
    }
}

// ---------------- launch ----------------
extern "C" void kernel_launch(void* const* d_in, const int* in_sizes, int n_in,
                              void* d_out, int out_size, void* d_ws, size_t ws_size,
                              hipStream_t stream) {
    const float* q_in = (const float*)d_in[0];
    const float* k_in = (const float*)d_in[1];
    const float* v_in = (const float*)d_in[2];
    // d_in[3] = causal mask — always tril, exploited structurally
    const float* wq = (const float*)d_in[4];
    const float* wk = (const float*)d_in[5];
    const float* wv = (const float*)d_in[6];
    const float* wo = (const float*)d_in[7];

    const size_t MD = (size_t)4096 * 1024;
    const size_t WD = (size_t)1024 * 1024;

    __hip_bfloat16* ws = (__hip_bfloat16*)d_ws;
    __hip_bfloat16* inb = ws;              // query,key,value bf16 (3*MD)
    __hip_bfloat16* wb = inb + 3 * MD;     // wq,wk,wv,wo bf16 (4*WD, stacked)
    __hip_bfloat16* Qbuf = wb + 4 * WD;    // MD
    __hip_bfloat16* Kbuf = Qbuf + MD;      // MD
    __hip_bfloat16* Vtb = Kbuf + MD;       // MD   [bh][64][2048]
    __hip_bfloat16* xb = Vtb + MD;         // MD   attention output

    cast_many<<<dim3(4096, 3), 256, 0, stream>>>(q_in, k_in, v_in, q_in, inb, MD, (int)(MD / 4));
    cast_many<<<dim3(1024, 4), 256, 0, stream>>>(wq, wk, wv, wo, wb, WD, (int)(WD / 4));

    // fused QKV projection, N=3072 (A chosen per region; V written transposed)
    gemm_bt<128, 1><<<dim3(24, 32), 256, 0, stream>>>(inb, wb, nullptr, Qbuf, Kbuf, Vtb);

    // causal attention (flat grid, XCD-swizzled)
    attn_causal<<<512, 256, 0, stream>>>(Qbuf, Kbuf, Vtb, xb);

    // output projection -> f32
    gemm_bt<64, 0><<<dim3(8, 64), 256, 0, stream>>>(xb, wb + 3 * WD, (float*)d_out,
                                                    nullptr, nullptr, nullptr);
}

// Round 4
// 223.079 us; speedup vs baseline: 1.6066x; 1.1273x over previous
//
#include <hip/hip_runtime.h>
#include <hip/hip_bf16.h>

// B=2, S=2048, D=1024, H=16, DH=64.  out = causal-MHA(q,k,v) @ wo.T
// bf16 MFMA path, f32 accumulation everywhere.

typedef __bf16 bf16x8 __attribute__((ext_vector_type(8)));
typedef float f32x4 __attribute__((ext_vector_type(4)));

#define AS1 __attribute__((address_space(1)))
#define AS3 __attribute__((address_space(3)))

__device__ __forceinline__ void load_lds16(const void* g, void* l) {
    __builtin_amdgcn_global_load_lds((const AS1 void*)g, (AS3 void*)l, 16, 0, 0);
}

// ---------------- f32 -> bf16 casts, up to 4 tensors per launch ----------------
__global__ __launch_bounds__(256) void cast_many(const float* __restrict__ a0,
                                                 const float* __restrict__ a1,
                                                 const float* __restrict__ a2,
                                                 const float* __restrict__ a3,
                                                 __hip_bfloat16* __restrict__ d,
                                                 size_t per, int n4) {
    const float* s = (blockIdx.y == 0) ? a0 : (blockIdx.y == 1) ? a1 : (blockIdx.y == 2) ? a2 : a3;
    d += (size_t)blockIdx.y * per;
    int i = blockIdx.x * 256 + threadIdx.x;
    if (i >= n4) return;
    float4 v = reinterpret_cast<const float4*>(s)[i];
    union { __hip_bfloat16 h[4]; short4 s4; } u;
    u.h[0] = __float2bfloat16(v.x);
    u.h[1] = __float2bfloat16(v.y);
    u.h[2] = __float2bfloat16(v.z);
    u.h[3] = __float2bfloat16(v.w);
    reinterpret_cast<short4*>(d)[i] = u.s4;
}

// ---------------- GEMM: C[M,N] = A[M,K] @ W[N,K]^T ----------------
// MODE 0: plain f32 output [4096][1024] (out projection), A = Ab.
// MODE 1: fused QKV (N=3072). A selected per n-region (query/key/value inputs).
//   region 0 -> Qb bf16 [4096][1024], scaled by 0.125 (1/sqrt(DH))
//   region 1 -> Kb bf16 [4096][1024]
//   region 2 -> Vtb bf16 [32 bh][64 dh][2048 s]  (transposed in epilogue)
template <int BM, int MODE>
__global__ __launch_bounds__(256) void gemm_bt(const __hip_bfloat16* __restrict__ Ab,
                                               const __hip_bfloat16* __restrict__ Wb,
                                               float* __restrict__ Cf,
                                               __hip_bfloat16* __restrict__ Qb,
                                               __hip_bfloat16* __restrict__ Kb,
                                               __hip_bfloat16* __restrict__ Vtb) {
    constexpr int Kn = 1024, BK = 32, MW = BM / 32;
    constexpr size_t MD = (size_t)4096 * 1024;

    __shared__ __hip_bfloat16 sA[BM * BK];
    __shared__ __hip_bfloat16 sB[128 * BK];

    const int t = threadIdx.x, w = t >> 6, l = t & 63;
    const int lr = l & 15, lk = (l >> 4) * 8;
    const int mbase = blockIdx.y * BM, nbase = blockIdx.x * 128;
    const int wr = (w >> 1) * (BM / 2), wc = (w & 1) * 64;

    const __hip_bfloat16* A = Ab;
    if constexpr (MODE == 1) A = Ab + (size_t)(nbase >> 10) * MD;

    f32x4 acc[MW][4] = {};

    for (int k0 = 0; k0 < Kn; k0 += BK) {
#pragma unroll
        for (int i = 0; i < BM / 64; i++) {
            const int c = i * 256 + t;
            load_lds16(&A[(size_t)(mbase + (c >> 2)) * Kn + k0 + (c & 3) * 8],
                       &sA[(i * 256 + w * 64) * 8]);
        }
#pragma unroll
        for (int i = 0; i < 2; i++) {
            const int c = i * 256 + t;
            load_lds16(&Wb[(size_t)(nbase + (c >> 2)) * Kn + k0 + (c & 3) * 8],
                       &sB[(i * 256 + w * 64) * 8]);
        }
        __syncthreads();
        bf16x8 af[MW], bfr[4];
#pragma unroll
        for (int m = 0; m < MW; m++) af[m] = *(const bf16x8*)&sA[(wr + m * 16 + lr) * BK + lk];
#pragma unroll
        for (int n = 0; n < 4; n++) bfr[n] = *(const bf16x8*)&sB[(wc + n * 16 + lr) * BK + lk];
#pragma unroll
        for (int m = 0; m < MW; m++)
#pragma unroll
            for (int n = 0; n < 4; n++)
                acc[m][n] = __builtin_amdgcn_mfma_f32_16x16x32_bf16(af[m], bfr[n], acc[m][n], 0, 0, 0);
        __syncthreads();
    }

    // C/D layout: col = lane&15, row = (lane>>4)*4 + reg
    const int row0 = mbase + wr + (l >> 4) * 4;
    if constexpr (MODE == 0) {
#pragma unroll
        for (int m = 0; m < MW; m++)
#pragma unroll
            for (int n = 0; n < 4; n++)
#pragma unroll
                for (int r = 0; r < 4; r++)
                    Cf[(size_t)(row0 + m * 16 + r) * 1024 + nbase + wc + n * 16 + lr] = acc[m][n][r];
    } else {
        const int region = nbase >> 10;
        const int colL = (nbase & 1023) + wc + lr;  // + n*16
        if (region < 2) {
            __hip_bfloat16* Ob = (region == 0) ? Qb : Kb;
            const float alpha = (region == 0) ? 0.125f : 1.0f;
#pragma unroll
            for (int m = 0; m < MW; m++)
#pragma unroll
                for (int n = 0; n < 4; n++)
#pragma unroll
                    for (int r = 0; r < 4; r++)
                        Ob[(size_t)(row0 + m * 16 + r) * 1024 + colL + n * 16] =
                            __float2bfloat16(acc[m][n][r] * alpha);
        } else {
            // V^T: Vtb[(b*16+h)*64 + dh][s], 4 consecutive tokens pack into 8B
#pragma unroll
            for (int m = 0; m < MW; m++) {
                const int s0 = row0 + m * 16;          // token (mult of 4)
                const int b = s0 >> 11, s = s0 & 2047;
#pragma unroll
                for (int n = 0; n < 4; n++) {
                    const int dhg = colL + n * 16;      // 0..1023
                    const size_t idx = ((size_t)((b * 16 + (dhg >> 6)) * 64 + (dhg & 63))) * 2048 + s;
                    union { __hip_bfloat16 h[4]; short4 s4; } u;
#pragma unroll
                    for (int r = 0; r < 4; r++) u.h[r] = __float2bfloat16(acc[m][n][r]);
                    *(short4*)&Vtb[idx] = u.s4;
                }
            }
        }
    }
}

// ---------------- causal flash attention (swapped QK^T, in-lane softmax) ----------------
// Q,K dense bf16 [4096][1024]; V^T [bh][64 dh][2048 s].
// One 64-row q-tile per block (grid 1024 = 4 blocks/CU), longest-first per XCD.
// Swapped S^T = mfma(K,Q): lane holds 16 kv-entries of ONE q-row -> in-lane softmax.
__device__ __forceinline__ bf16x8 rd8(const __hip_bfloat16* tile, int row, int colb) {
    return *(const bf16x8*)((const char*)tile + row * 128 + (colb ^ ((row & 7) << 4)));
}

__device__ __forceinline__ void stage_kv(const char* Kg, const char* Vg, void* ksb, void* vsb, int t) {
#pragma unroll
    for (int i = 0; i < 2; i++) {
        const int c = i * 256 + t, row = c >> 3;
        const int colb = ((c & 7) * 16) ^ ((row & 7) << 4);
        load_lds16(Kg + (size_t)row * 2048 + colb, (char*)ksb + (i * 256 + (t & 192)) * 16);
    }
#pragma unroll
    for (int i = 0; i < 2; i++) {
        const int c = i * 256 + t, row = c >> 3;
        const int colb = ((c & 7) * 16) ^ ((row & 7) << 4);
        load_lds16(Vg + (size_t)row * 4096 + colb, (char*)vsb + (i * 256 + (t & 192)) * 16);
    }
}

__global__ __launch_bounds__(256, 4) void attn_causal(const __hip_bfloat16* __restrict__ Qb,
                                                      const __hip_bfloat16* __restrict__ Kb,
                                                      const __hip_bfloat16* __restrict__ Vtb,
                                                      __hip_bfloat16* __restrict__ X) {
    constexpr int S = 2048;
    // grid 1024: xcd = i&7 (HW round-robin), 4 bh per XCD (L2-resident K/V),
    // qt descending within XCD -> longest blocks dispatch first.
    const int i0 = blockIdx.x;
    const int j = i0 >> 3;
    const int bh = (i0 & 7) * 4 + (j & 3);
    const int qt = 31 - (j >> 2);
    const int b = bh >> 4, h = bh & 15;

    __shared__ __hip_bfloat16 Ks[2][4096];  // [64 kv][64 dh] swizzled
    __shared__ __hip_bfloat16 Vs[2][4096];  // [64 dh][64 kv] swizzled
    __shared__ __hip_bfloat16 Pl[4 * 1024]; // per-wave [16 q][64 kv] swizzled

    const int t = threadIdx.x, w = t >> 6, l = t & 63;
    const int lr = l & 15, lg = l >> 4, lk = lg * 8;

    const __hip_bfloat16* Qbh = Qb + (size_t)b * S * 1024 + h * 64;
    const char* Kbh = (const char*)(Kb + (size_t)b * S * 1024 + h * 64);
    const char* Vbh = (const char*)(Vtb + (size_t)bh * 64 * 2048);
    __hip_bfloat16* Xbh = X + (size_t)b * S * 1024 + h * 64;

    const int qrow = qt * 64 + w * 16;
    bf16x8 qf[2];
#pragma unroll
    for (int kk = 0; kk < 2; kk++)
        qf[kk] = *(const bf16x8*)&Qbh[(size_t)(qrow + lr) * 1024 + kk * 32 + lk];

    f32x4 xacc[4] = {};
    float m = -1e30f, lsum = 0.f;  // softmax state for q = qrow + lr (per lane)

    stage_kv(Kbh, Vbh, &Ks[0][0], &Vs[0][0], t);

    const int total = qt + 1;
    for (int kt = 0; kt < total; ++kt) {
        if (kt + 1 < total) {
            stage_kv(Kbh + (size_t)((kt + 1) * 64) * 2048, Vbh + (size_t)(kt + 1) * 128,
                     &Ks[(kt + 1) & 1][0], &Vs[(kt + 1) & 1][0], t);
            asm volatile("s_waitcnt vmcnt(4)" ::: "memory");
        } else {
            asm volatile("s_waitcnt vmcnt(0)" ::: "memory");
        }
        __builtin_amdgcn_s_barrier();

        const __hip_bfloat16* Kt = &Ks[kt & 1][0];
        const __hip_bfloat16* Vt = &Vs[kt & 1][0];

        // ---- S^T = K @ Q^T : lane holds S[kv = n*16 + lg*4 + r][q = qrow + lr] ----
        f32x4 sacc[4] = {};
#pragma unroll
        for (int kk = 0; kk < 2; kk++)
#pragma unroll
            for (int n = 0; n < 4; n++)
                sacc[n] = __builtin_amdgcn_mfma_f32_16x16x32_bf16(
                    rd8(Kt, n * 16 + lr, kk * 64 + lg * 16), qf[kk], sacc[n], 0, 0, 0);

        // ---- causal mask on diagonal tile ----
        if (kt == qt) {
            const int qg = qrow + lr;
#pragma unroll
            for (int n = 0; n < 4; n++)
#pragma unroll
                for (int r = 0; r < 4; r++)
                    if (kt * 64 + n * 16 + lg * 4 + r > qg) sacc[n][r] = -1e30f;
        }

        // ---- in-lane softmax over this lane's 16 kv entries + 2-shfl reduce ----
        float tm = -1e30f;
#pragma unroll
        for (int n = 0; n < 4; n++) {
            float a = fmaxf(fmaxf(sacc[n][0], sacc[n][1]), fmaxf(sacc[n][2], sacc[n][3]));
            tm = fmaxf(tm, a);
        }
        tm = fmaxf(tm, __shfl_xor(tm, 16, 64));
        tm = fmaxf(tm, __shfl_xor(tm, 32, 64));
        const float mn = fmaxf(m, tm);
        const float sc = __expf(m - mn);
        m = mn;
        float pr[4][4], ps = 0.f;
#pragma unroll
        for (int n = 0; n < 4; n++)
#pragma unroll
            for (int r = 0; r < 4; r++) {
                const float pv = __expf(sacc[n][r] - mn);
                pr[n][r] = pv;
                ps += pv;
            }
        ps += __shfl_xor(ps, 16, 64);
        ps += __shfl_xor(ps, 32, 64);
        lsum = lsum * sc + ps;

        // ---- broadcast rescale factor to xacc's q-rows (q = lg*4 + r) ----
#pragma unroll
        for (int r = 0; r < 4; r++) {
            const float bsc = __shfl(sc, (lg << 2) + r, 64);
#pragma unroll
            for (int dd = 0; dd < 4; dd++) xacc[dd][r] *= bsc;
        }

        // ---- P^T -> per-wave LDS (row = q = lr, 4 consecutive kv pack to b64) ----
#pragma unroll
        for (int n = 0; n < 4; n++) {
            union { __hip_bfloat16 hh[4]; short4 s4; } u;
#pragma unroll
            for (int r = 0; r < 4; r++) u.hh[r] = __float2bfloat16(pr[n][r]);
            *(short4*)((char*)Pl + w * 2048 + lr * 128 +
                       ((n * 32 + lg * 8) ^ ((lr & 7) << 4))) = u.s4;
        }

        // ---- PV: X[16 q][64 dh] += P @ V ----
#pragma unroll
        for (int kk = 0; kk < 2; kk++) {
            const bf16x8 pa = *(const bf16x8*)((const char*)Pl + w * 2048 + lr * 128 +
                                               ((kk * 64 + lg * 16) ^ ((lr & 7) << 4)));
#pragma unroll
            for (int dd = 0; dd < 4; dd++)
                xacc[dd] = __builtin_amdgcn_mfma_f32_16x16x32_bf16(
                    pa, rd8(Vt, dd * 16 + lr, kk * 64 + lg * 16), xacc[dd], 0, 0, 0);
        }
        __builtin_amdgcn_s_barrier();
    }

    // ---- epilogue: broadcast 1/lsum to xacc lanes, store ----
    const float inv = 1.0f / lsum;
#pragma unroll
    for (int r = 0; r < 4; r++) {
        const float binv = __shfl(inv, (lg << 2) + r, 64);
#pragma unroll
        for (int dd = 0; dd < 4; dd++)
            Xbh[(size_t)(qrow + lg * 4 + r) * 1024 + dd * 16 + lr] =
                __float2bfloat16(xacc[dd][r] * binv);
    }
}

// ---------------- launch ----------------
extern "C" void kernel_launch(void* const* d_in, const int* in_sizes, int n_in,
                              void* d_out, int out_size, void* d_ws, size_t ws_size,
                              hipStream_t stream) {
    const float* q_in = (const float*)d_in[0];
    const float* k_in = (const float*)d_in[1];
    const float* v_in = (const float*)d_in[2];
    // d_in[3] = causal mask — always tril, exploited structurally
    const float* wq = (const float*)d_in[4];
    const float* wk = (const float*)d_in[5];
    const float* wv = (const float*)d_in[6];
    const float* wo = (const float*)d_in[7];

    const size_t MD = (size_t)4096 * 1024;
    const size_t WD = (size_t)1024 * 1024;

    __hip_bfloat16* ws = (__hip_bfloat16*)d_ws;
    __hip_bfloat16* inb = ws;              // query,key,value bf16 (3*MD)
    __hip_bfloat16* wb = inb + 3 * MD;     // wq,wk,wv,wo bf16 (4*WD, stacked)
    __hip_bfloat16* Qbuf = wb + 4 * WD;    // MD
    __hip_bfloat16* Kbuf = Qbuf + MD;      // MD
    __hip_bfloat16* Vtb = Kbuf + MD;       // MD   [bh][64][2048]
    __hip_bfloat16* xb = Vtb + MD;         // MD   attention output

    cast_many<<<dim3(4096, 3), 256, 0, stream>>>(q_in, k_in, v_in, q_in, inb, MD, (int)(MD / 4));
    cast_many<<<dim3(1024, 4), 256, 0, stream>>>(wq, wk, wv, wo, wb, WD, (int)(WD / 4));

    // fused QKV projection, N=3072 (A chosen per region; V written transposed)
    gemm_bt<128, 1><<<dim3(24, 32), 256, 0, stream>>>(inb, wb, nullptr, Qbuf, Kbuf, Vtb);

    // causal attention (per-q-tile blocks, longest-first, XCD-local K/V)
    attn_causal<<<1024, 256, 0, stream>>>(Qbuf, Kbuf, Vtb, xb);

    // output projection -> f32
    gemm_bt<64, 0><<<dim3(8, 64), 256, 0, stream>>>(xb, wb + 3 * WD, (float*)d_out,
                                                    nullptr, nullptr, nullptr);
}